// Round 19
// baseline (336.825 us; speedup 1.0000x reference)
//
#include <hip/hip_runtime.h>
#include <hip/hip_bf16.h>

typedef __attribute__((ext_vector_type(8))) short short8;
typedef __attribute__((ext_vector_type(4))) float f32x4;

constexpr int SEQ = 16384, BATCH = 8, DIN = 256, NQKV = 768;
constexpr float SCALE = 0.17677669529663687f; // 32^-0.5
constexpr float EPS = 1e-5f;

__device__ __forceinline__ unsigned short f2bf(float f){
  __hip_bfloat16 h = __float2bfloat16(f);
  unsigned short u; __builtin_memcpy(&u, &h, 2); return u;
}
__device__ __forceinline__ float bf2f(unsigned short h){
  return __uint_as_float(((unsigned int)h) << 16);
}
__device__ __forceinline__ void gload_lds16(const void* g, void* l){
  __builtin_amdgcn_global_load_lds(
    (const __attribute__((address_space(1))) unsigned int*)g,
    (__attribute__((address_space(3))) unsigned int*)l, 16, 0, 0);
}

// ---- K0: Wqkv [256 x 768] fp32 -> WT [768 x 256] bf16 (transposed) ----
__global__ void k_wt(const float* __restrict__ W, unsigned short* __restrict__ WT){
  int id = blockIdx.x * 256 + threadIdx.x;
  int k = id / NQKV, n = id % NQKV;
  WT[n * DIN + k] = f2bf(W[id]);
}

// ---- K1: BARRIER-FREE fused qkv GEMM + k-exp + wave-local ctx Gram.
// 1024 blocks x 256 thr. A in regs; B fragments loaded DIRECT from global
// (WT = 393 KB, L2-resident) -> no B staging, no staging barriers. ctx Gram
// is wave-local (K=32 over the wave's own tokens, wave-private LDS transpose
// tiles, same-wave in-order LDS -> no barrier), accumulated across waves via
// LDS atomicAdd. Only 2 barriers in the whole kernel (init / flush); waves
// free-run so 12 waves/CU hide L2+LDS latency (the r11..r18 plateau was
// barrier-convoying: MfmaUtil == MFMA-floor/dur exactly). ----
__global__ __launch_bounds__(256) void k_qkv(const float* __restrict__ X,
                                             const unsigned short* __restrict__ WT,
                                             unsigned short* __restrict__ Q,
                                             float* __restrict__ ctxp,
                                             float* __restrict__ sumwp){
  __shared__ unsigned short Tw[4][32][34];   // wave-private w^T tiles, 8.7 KB
  __shared__ unsigned short Tv[4][32][34];   // wave-private v^T tiles, 8.7 KB
  __shared__ float ctx_lds[8 * 1056];        // [h][d][e] stride 33, 33.8 KB
  __shared__ float sumLds[256];
  const int blk = blockIdx.x;
  const size_t m0 = (size_t)blk * 128;
  const int tid = threadIdx.x, wave = tid >> 6, lane = tid & 63;
  const int lg = lane >> 4, li = lane & 15;

  // init accumulators (barrier 1 below)
  for (int i = tid; i < 8448; i += 256) ctx_lds[i] = 0.f;
  sumLds[tid] = 0.f;

  auto panelN0 = [](int p){
    return (p < 16) ? (((p & 1) ? 512 : 256) + (p >> 1) * 32) : (p - 16) * 32;
  };

  // A fragments: 32 rows/wave, full K=256, fp32 -> bf16 (64 VGPR)
  short8 afrag[2][8];
  #pragma unroll
  for (int rt = 0; rt < 2; rt++){
    const float* xr = X + (m0 + wave * 32 + rt * 16 + li) * 256 + lg * 8;
    #pragma unroll
    for (int ks = 0; ks < 8; ks++){
      float4 f0 = *reinterpret_cast<const float4*>(xr + ks * 32);
      float4 f1 = *reinterpret_cast<const float4*>(xr + ks * 32 + 4);
      short8 a;
      a[0] = f2bf(f0.x); a[1] = f2bf(f0.y); a[2] = f2bf(f0.z); a[3] = f2bf(f0.w);
      a[4] = f2bf(f1.x); a[5] = f2bf(f1.y); a[6] = f2bf(f1.z); a[7] = f2bf(f1.w);
      afrag[rt][ks] = a;
    }
  }
  #pragma unroll
  for (int rt = 0; rt < 2; rt++)
    #pragma unroll
    for (int ks = 0; ks < 8; ks++)
      asm volatile("" : "+v"(afrag[rt][ks]));
  __syncthreads();   // barrier 1: ctx_lds/sumLds init visible to all waves

  const f32x4 zf = {0.f, 0.f, 0.f, 0.f};
  // per-lane B base: row (n0 + j*16 + li), cols ks*32 + lg*8
  const unsigned short* wtl = WT + (size_t)li * 256 + lg * 8;

  #pragma unroll 1
  for (int p = 0; p < 24; ++p){
    const int n0 = panelN0(p);
    const unsigned short* b0p = wtl + (size_t)n0 * 256;
    const unsigned short* b1p = b0p + 16 * 256;
    // ---- panel matmul: B direct from global (L2-hit), 32 MFMAs/wave ----
    f32x4 acc[2][2];
    acc[0][0] = zf; acc[0][1] = zf; acc[1][0] = zf; acc[1][1] = zf;
    #pragma unroll
    for (int ks = 0; ks < 8; ks++){
      short8 b0 = *reinterpret_cast<const short8*>(b0p + ks * 32);
      short8 b1 = *reinterpret_cast<const short8*>(b1p + ks * 32);
      acc[0][0] = __builtin_amdgcn_mfma_f32_16x16x32_bf16(afrag[0][ks], b0, acc[0][0], 0, 0, 0);
      acc[1][0] = __builtin_amdgcn_mfma_f32_16x16x32_bf16(afrag[1][ks], b0, acc[1][0], 0, 0, 0);
      acc[0][1] = __builtin_amdgcn_mfma_f32_16x16x32_bf16(afrag[0][ks], b1, acc[0][1], 0, 0, 0);
      acc[1][1] = __builtin_amdgcn_mfma_f32_16x16x32_bf16(afrag[1][ks], b1, acc[1][1], 0, 0, 0);
    }
    // ---- epilogue (all wave-local; NO barriers) ----
    if (p < 16){
      int h = p >> 1;
      if (!(p & 1)){
        // K panel: w = exp(k) (k ~ N(0,1), safe); wave-private transpose + col sums
        #pragma unroll
        for (int j = 0; j < 2; j++){
          float cs = 0.f;
          #pragma unroll
          for (int rt = 0; rt < 2; rt++){
            unsigned short h0 = f2bf(__expf(acc[rt][j][0]));
            unsigned short h1 = f2bf(__expf(acc[rt][j][1]));
            unsigned short h2 = f2bf(__expf(acc[rt][j][2]));
            unsigned short h3 = f2bf(__expf(acc[rt][j][3]));
            cs += bf2f(h0) + bf2f(h1) + bf2f(h2) + bf2f(h3);
            ushort4 pk; pk.x = h0; pk.y = h1; pk.z = h2; pk.w = h3;
            *reinterpret_cast<ushort4*>(&Tw[wave][j * 16 + li][rt * 16 + lg * 4]) = pk;
          }
          cs += __shfl_xor(cs, 16); cs += __shfl_xor(cs, 32);
          if (lane < 16) atomicAdd(&sumLds[h * 32 + j * 16 + li], cs);
        }
      } else {
        // V panel: wave-private transpose, then wave-local ctx Gram (K=32)
        #pragma unroll
        for (int j = 0; j < 2; j++)
          #pragma unroll
          for (int rt = 0; rt < 2; rt++){
            ushort4 pk;
            pk.x = f2bf(acc[rt][j][0]); pk.y = f2bf(acc[rt][j][1]);
            pk.z = f2bf(acc[rt][j][2]); pk.w = f2bf(acc[rt][j][3]);
            *reinterpret_cast<ushort4*>(&Tv[wave][j * 16 + li][rt * 16 + lg * 4]) = pk;
          }
        // same-wave LDS ops are in-order; compiler inserts lgkmcnt waits
        #pragma unroll
        for (int dh = 0; dh < 2; dh++)
          #pragma unroll
          for (int eh = 0; eh < 2; eh++){
            short8 aw = *reinterpret_cast<const short8*>(&Tw[wave][dh * 16 + li][lg * 8]);
            short8 bv = *reinterpret_cast<const short8*>(&Tv[wave][eh * 16 + li][lg * 8]);
            f32x4 c = __builtin_amdgcn_mfma_f32_16x16x32_bf16(aw, bv, zf, 0, 0, 0);
            #pragma unroll
            for (int r = 0; r < 4; r++)
              atomicAdd(&ctx_lds[h * 1056 + (dh * 16 + lg * 4 + r) * 33 + eh * 16 + li], c[r]);
          }
      }
    } else {
      // Q panel (head ph): raw bf16 direct stores (softmax deferred to k_out)
      int ph = p - 16;
      #pragma unroll
      for (int rt = 0; rt < 2; rt++)
        #pragma unroll
        for (int j = 0; j < 2; j++)
          #pragma unroll
          for (int r = 0; r < 4; r++)
            Q[(m0 + wave * 32 + rt * 16 + lg * 4 + r) * 256 + ph * 32 + j * 16 + li]
              = f2bf(acc[rt][j][r]);
    }
  }
  __syncthreads();   // barrier 2: all atomics done
  // flush ctx accumulator (strip the pad) and sums
  for (int i = tid; i < 8192; i += 256){
    int h = i >> 10, de = i & 1023;
    ctxp[(size_t)blk * 8192 + i] = ctx_lds[h * 1056 + (de >> 5) * 33 + (de & 31)];
  }
  sumwp[(size_t)blk * 256 + tid] = sumLds[tid];
}

// ---- K2a: reduce ctx partials 128 -> 16 chunks (full-chip parallel) ----
__global__ __launch_bounds__(256) void k_red1(const float* __restrict__ ctxp,
                                              const float* __restrict__ sumwp,
                                              float* __restrict__ ctxr,
                                              float* __restrict__ sumr){
  int bid = blockIdx.x;              // ((b*8+h)*16+s)
  int s = bid & 15, bh = bid >> 4;
  int b = bh >> 3, h = bh & 7;
  int t = threadIdx.x;
  float a[4] = {0.f, 0.f, 0.f, 0.f};
  #pragma unroll
  for (int k = 0; k < 8; k++){
    const float* cp = ctxp + ((size_t)(b * 128 + s * 8 + k) * 8 + h) * 1024;
    #pragma unroll
    for (int q = 0; q < 4; q++) a[q] += cp[q * 256 + t];
  }
  float* orow = ctxr + (size_t)bid * 1024;
  #pragma unroll
  for (int q = 0; q < 4; q++) orow[q * 256 + t] = a[q];
  if (t < 32){
    float sw = 0.f;
    #pragma unroll
    for (int k = 0; k < 8; k++)
      sw += sumwp[(size_t)(b * 128 + s * 8 + k) * 256 + h * 32 + t];
    sumr[(size_t)bid * 32 + t] = sw;
  }
}

// ---- K2b: final reduce, /sumw, fold Wout -> MT[b][j][hd] bf16 ----
__global__ __launch_bounds__(256) void k_build_m(const float* __restrict__ ctxr,
                                                 const float* __restrict__ sumr,
                                                 const float* __restrict__ Wout,
                                                 unsigned short* __restrict__ MT){
  __shared__ float ctxs[32][33];
  __shared__ float swb[32];
  int b = blockIdx.x >> 3, h = blockIdx.x & 7;
  int bh16 = (b * 8 + h) * 16;
  int t = threadIdx.x;
  int e = t & 31, dq = t >> 5;
  float a0 = 0.f, a1 = 0.f, a2 = 0.f, a3 = 0.f;
  #pragma unroll
  for (int s = 0; s < 16; s++){
    const float* cp = ctxr + (size_t)(bh16 + s) * 1024;
    a0 += cp[dq * 32 + e];         a1 += cp[(dq + 8) * 32 + e];
    a2 += cp[(dq + 16) * 32 + e];  a3 += cp[(dq + 24) * 32 + e];
  }
  if (t < 32){
    float sw = 0.f;
    #pragma unroll
    for (int s = 0; s < 16; s++) sw += sumr[(size_t)(bh16 + s) * 32 + t];
    swb[t] = sw;
  }
  __syncthreads();
  ctxs[dq][e]      = a0 / swb[dq];
  ctxs[dq + 8][e]  = a1 / swb[dq + 8];
  ctxs[dq + 16][e] = a2 / swb[dq + 16];
  ctxs[dq + 24][e] = a3 / swb[dq + 24];
  __syncthreads();
  float s[32];
  #pragma unroll
  for (int d = 0; d < 32; d++) s[d] = 0.f;
  for (int ee = 0; ee < 32; ee++){
    float wv = Wout[(size_t)(h * 32 + ee) * 256 + t];
    #pragma unroll
    for (int d = 0; d < 32; d++) s[d] += ctxs[d][ee] * wv;
  }
  unsigned short* mp = MT + (size_t)b * 65536 + (size_t)t * 256 + h * 32;
  #pragma unroll
  for (int d8 = 0; d8 < 4; d8++){
    short8 pk;
    #pragma unroll
    for (int q = 0; q < 8; q++) pk[q] = (short)f2bf(s[d8 * 8 + q]);
    *reinterpret_cast<short8*>(mp + d8 * 8) = pk;
  }
}

// ---- K3: out = LN( softmax_q(q) @ MT^T ) * gamma ; softmax fused here
// (memory-bound kernel, VALU is free). 2048 blocks x 256 thr, 64 rows/block. ----
__global__ __launch_bounds__(256, 4) void k_out(const unsigned short* __restrict__ Qm,
                                                const unsigned short* __restrict__ MT,
                                                const float* __restrict__ gamma,
                                                float* __restrict__ out){
  __shared__ unsigned short Bs[64 * 256];  // 32 KB swizzled
  const int blk = blockIdx.x;
  const int b = blk >> 8;
  const size_t m0 = (size_t)blk * 64;
  const int tid = threadIdx.x, wave = tid >> 6, lane = tid & 63;
  const int lg = lane >> 4, li = lane & 15;

  short8 afrag[8];
  {
    const unsigned short* qr = Qm + (m0 + wave * 16 + li) * 256 + lg * 8;
    #pragma unroll
    for (int ks = 0; ks < 8; ks++)
      afrag[ks] = *reinterpret_cast<const short8*>(qr + ks * 32);
  }
  // deferred q-softmax: head ks = cols ks*32..+31; lane holds 8 (lg*8..+7)
  #pragma unroll
  for (int ks = 0; ks < 8; ks++){
    float v[8];
    #pragma unroll
    for (int q = 0; q < 8; q++) v[q] = bf2f((unsigned short)afrag[ks][q]);
    float mx = v[0];
    #pragma unroll
    for (int q = 1; q < 8; q++) mx = fmaxf(mx, v[q]);
    mx = fmaxf(mx, __shfl_xor(mx, 16));
    mx = fmaxf(mx, __shfl_xor(mx, 32));
    float s = 0.f;
    #pragma unroll
    for (int q = 0; q < 8; q++){ v[q] = __expf(v[q] - mx); s += v[q]; }
    s += __shfl_xor(s, 16);
    s += __shfl_xor(s, 32);
    float iv = SCALE / s;
    #pragma unroll
    for (int q = 0; q < 8; q++) afrag[ks][q] = (short)f2bf(v[q] * iv);
  }

  const char* mtb = (const char*)MT + (size_t)b * 131072;
  f32x4 acc[4][4];
  const f32x4 zf = {0.f, 0.f, 0.f, 0.f};
  #pragma unroll
  for (int jb = 0; jb < 4; jb++)
    #pragma unroll
    for (int j = 0; j < 4; j++) acc[jb][j] = zf;

  #pragma unroll
  for (int jb = 0; jb < 4; jb++){
    if (jb) __syncthreads();
    #pragma unroll
    for (int rr = 0; rr < 8; rr++){
      int L = rr * 4096 + tid * 16;
      int G = L ^ (((L >> 9) & 7) << 4);   // pre-swizzled source (rule 21)
      gload_lds16(mtb + (size_t)jb * 32768 + G, (char*)Bs + L);
    }
    __syncthreads();
    #pragma unroll
    for (int ks = 0; ks < 8; ks++)
      #pragma unroll
      for (int j = 0; j < 4; j++){
        int n = j * 16 + li;
        int L = n * 512 + (ks * 32 + lg * 8) * 2;
        short8 bb = *reinterpret_cast<const short8*>((const char*)Bs + (L ^ ((n & 7) << 4)));
        acc[jb][j] = __builtin_amdgcn_mfma_f32_16x16x32_bf16(afrag[ks], bb, acc[jb][j], 0, 0, 0);
      }
  }

  float gam[16];
  #pragma unroll
  for (int jb = 0; jb < 4; jb++)
    #pragma unroll
    for (int j = 0; j < 4; j++) gam[jb * 4 + j] = gamma[jb * 64 + j * 16 + li];
  #pragma unroll
  for (int r = 0; r < 4; r++){
    float s = 0.f, qq = 0.f;
    #pragma unroll
    for (int jb = 0; jb < 4; jb++)
      #pragma unroll
      for (int j = 0; j < 4; j++){ float v = acc[jb][j][r]; s += v; qq += v * v; }
    #pragma unroll
    for (int mm = 1; mm < 16; mm <<= 1){ s += __shfl_xor(s, mm); qq += __shfl_xor(qq, mm); }
    float mu = s * (1.f / 256.f);
    float var = qq * (1.f / 256.f) - mu * mu;
    float inv = rsqrtf(var + EPS);
    float* op = out + (m0 + wave * 16 + lg * 4 + r) * 256;
    #pragma unroll
    for (int jb = 0; jb < 4; jb++)
      #pragma unroll
      for (int j = 0; j < 4; j++)
        op[jb * 64 + j * 16 + li] = (acc[jb][j][r] - mu) * inv * gam[jb * 4 + j];
  }
}

extern "C" void kernel_launch(void* const* d_in, const int* in_sizes, int n_in,
                              void* d_out, int out_size, void* d_ws, size_t ws_size,
                              hipStream_t stream){
  const float* x     = (const float*)d_in[0];
  const float* Wqkv  = (const float*)d_in[1];
  const float* Wout  = (const float*)d_in[2];
  const float* gamma = (const float*)d_in[3];
  float* out = (float*)d_out;

  char* ws = (char*)d_ws;
  size_t off = 0;
  unsigned short* Q   = (unsigned short*)(ws + off); off += (size_t)BATCH * SEQ * 256 * 2;   // 67 MB
  unsigned short* WT  = (unsigned short*)(ws + off); off += (size_t)NQKV * DIN * 2;
  float* ctxp         = (float*)(ws + off);          off += (size_t)1024 * 8 * 1024 * 4;     // 33.6 MB
  float* sumwp        = (float*)(ws + off);          off += (size_t)1024 * 256 * 4;
  float* ctxr         = (float*)(ws + off);          off += (size_t)1024 * 1024 * 4;
  float* sumr         = (float*)(ws + off);          off += (size_t)1024 * 32 * 4;
  unsigned short* MT  = (unsigned short*)(ws + off); off += (size_t)BATCH * 65536 * 2;

  k_wt<<<(NQKV * DIN) / 256, 256, 0, stream>>>(Wqkv, WT);
  k_qkv<<<1024, 256, 0, stream>>>(x, WT, Q, ctxp, sumwp);
  k_red1<<<1024, 256, 0, stream>>>(ctxp, sumwp, ctxr, sumr);
  k_build_m<<<64, 256, 0, stream>>>(ctxr, sumr, Wout, MT);
  k_out<<<2048, 256, 0, stream>>>(Q, MT, gamma, out);
}

// Round 20
// 175.919 us; speedup vs baseline: 1.9147x; 1.9147x over previous
//
#include <hip/hip_runtime.h>
#include <hip/hip_bf16.h>

typedef __attribute__((ext_vector_type(8))) short short8;
typedef __attribute__((ext_vector_type(4))) float f32x4;

constexpr int SEQ = 16384, BATCH = 8, DIN = 256, NQKV = 768;
constexpr float SCALE = 0.17677669529663687f; // 32^-0.5
constexpr float EPS = 1e-5f;

__device__ __forceinline__ unsigned short f2bf(float f){
  __hip_bfloat16 h = __float2bfloat16(f);
  unsigned short u; __builtin_memcpy(&u, &h, 2); return u;
}
__device__ __forceinline__ float bf2f(unsigned short h){
  return __uint_as_float(((unsigned int)h) << 16);
}
__device__ __forceinline__ void gload_lds16(const void* g, void* l){
  __builtin_amdgcn_global_load_lds(
    (const __attribute__((address_space(1))) unsigned int*)g,
    (__attribute__((address_space(3))) unsigned int*)l, 16, 0, 0);
}
// LDS-only barrier: drains own LDS ops then syncs; does NOT drain global stores.
__device__ __forceinline__ void lds_barrier(){
  asm volatile("s_waitcnt lgkmcnt(0)" ::: "memory");
  __builtin_amdgcn_s_barrier();
}

// ---- K0: Wqkv [256 x 768] fp32 -> WT [768 x 256] bf16 (transposed) ----
__global__ void k_wt(const float* __restrict__ W, unsigned short* __restrict__ WT){
  int id = blockIdx.x * 256 + threadIdx.x;
  int k = id / NQKV, n = id % NQKV;
  WT[n * DIN + k] = f2bf(W[id]);
}

// ---- K1: fused qkv GEMM + k-exp + ctx Gram (q-softmax deferred to k_out).
// r18 verbatim (best measured: 121 us, passed). 1024 blocks x 256 thr,
// double-buffered Bs via global_load_lds, 32 barrier-phases. ----
__global__ __launch_bounds__(256) void k_qkv(const float* __restrict__ X,
                                             const unsigned short* __restrict__ WT,
                                             unsigned short* __restrict__ Q,
                                             float* __restrict__ ctxp,
                                             float* __restrict__ sumwp){
  __shared__ unsigned short Bs[2][32 * 256];   // 16 KB each, swizzle byte^=((row&7)<<4)
  __shared__ unsigned short WVs[2][32][136];   // w^T / v^T, 17.4 KB
  __shared__ float sumLds[256];
  const int blk = blockIdx.x;
  const size_t m0 = (size_t)blk * 128;
  const int tid = threadIdx.x, wave = tid >> 6, lane = tid & 63;
  const int lg = lane >> 4, li = lane & 15;
  sumLds[tid] = 0.f;

  auto panelN0 = [](int p){
    return (p < 16) ? (((p & 1) ? 512 : 256) + (p >> 1) * 32) : (p - 16) * 32;
  };
  auto stageB = [&](int buf, int n0){
    #pragma unroll
    for (int it = 0; it < 4; it++){
      int L = (it * 256 + tid) * 16;
      int G = L ^ (((L >> 9) & 7) << 4);       // pre-swizzled source (rule 21)
      gload_lds16((const char*)WT + (size_t)(n0 + (L >> 9)) * 512 + (G & 511),
                  (char*)Bs[buf] + L);
    }
  };

  // prologue: stage panel 0; A fragments fp32->bf16 in regs (64 VGPR)
  stageB(0, panelN0(0));
  short8 afrag[2][8];
  #pragma unroll
  for (int rt = 0; rt < 2; rt++){
    const float* xr = X + (m0 + wave * 32 + rt * 16 + li) * 256 + lg * 8;
    #pragma unroll
    for (int ks = 0; ks < 8; ks++){
      float4 f0 = *reinterpret_cast<const float4*>(xr + ks * 32);
      float4 f1 = *reinterpret_cast<const float4*>(xr + ks * 32 + 4);
      short8 a;
      a[0] = f2bf(f0.x); a[1] = f2bf(f0.y); a[2] = f2bf(f0.z); a[3] = f2bf(f0.w);
      a[4] = f2bf(f1.x); a[5] = f2bf(f1.y); a[6] = f2bf(f1.z); a[7] = f2bf(f1.w);
      afrag[rt][ks] = a;
    }
  }
  #pragma unroll
  for (int rt = 0; rt < 2; rt++)
    #pragma unroll
    for (int ks = 0; ks < 8; ks++)
      asm volatile("" : "+v"(afrag[rt][ks]));
  __syncthreads();   // drains stage(0)

  const f32x4 zf = {0.f, 0.f, 0.f, 0.f};
  int buf = 0;
  #pragma unroll 1
  for (int p = 0; p < 24; ++p){
    if (p < 23) stageB(buf ^ 1, panelN0(p + 1));   // async into free buffer
    // ---- panel matmul: 32 MFMAs/wave from Bs[buf] ----
    f32x4 acc[2][2];
    acc[0][0] = zf; acc[0][1] = zf; acc[1][0] = zf; acc[1][1] = zf;
    __builtin_amdgcn_s_setprio(1);
    #pragma unroll
    for (int ks = 0; ks < 8; ks++)
      #pragma unroll
      for (int j = 0; j < 2; j++){
        int nl = j * 16 + li;
        int L = nl * 512 + (ks * 32 + lg * 8) * 2;
        short8 bb = *reinterpret_cast<const short8*>((const char*)Bs[buf] + (L ^ ((nl & 7) << 4)));
        acc[0][j] = __builtin_amdgcn_mfma_f32_16x16x32_bf16(afrag[0][ks], bb, acc[0][j], 0, 0, 0);
        acc[1][j] = __builtin_amdgcn_mfma_f32_16x16x32_bf16(afrag[1][ks], bb, acc[1][j], 0, 0, 0);
      }
    __builtin_amdgcn_s_setprio(0);
    // ---- epilogue ----
    if (p < 16){
      int h = p >> 1;
      if (!(p & 1)){
        // K panel (head h): w = exp(k) (k ~ N(0,1), safe), stage w^T + col sums
        #pragma unroll
        for (int j = 0; j < 2; j++){
          float cs = 0.f;
          #pragma unroll
          for (int rt = 0; rt < 2; rt++){
            unsigned short h0 = f2bf(__expf(acc[rt][j][0]));
            unsigned short h1 = f2bf(__expf(acc[rt][j][1]));
            unsigned short h2 = f2bf(__expf(acc[rt][j][2]));
            unsigned short h3 = f2bf(__expf(acc[rt][j][3]));
            cs += bf2f(h0) + bf2f(h1) + bf2f(h2) + bf2f(h3);
            ushort4 pk; pk.x = h0; pk.y = h1; pk.z = h2; pk.w = h3;
            *reinterpret_cast<ushort4*>(&WVs[0][j * 16 + li][wave * 32 + rt * 16 + lg * 4]) = pk;
          }
          cs += __shfl_xor(cs, 16); cs += __shfl_xor(cs, 32);
          if (lane < 16) atomicAdd(&sumLds[h * 32 + j * 16 + li], cs);
        }
      } else {
        // V panel: stage v^T
        #pragma unroll
        for (int j = 0; j < 2; j++)
          #pragma unroll
          for (int rt = 0; rt < 2; rt++){
            ushort4 pk;
            pk.x = f2bf(acc[rt][j][0]); pk.y = f2bf(acc[rt][j][1]);
            pk.z = f2bf(acc[rt][j][2]); pk.w = f2bf(acc[rt][j][3]);
            *reinterpret_cast<ushort4*>(&WVs[1][j * 16 + li][wave * 32 + rt * 16 + lg * 4]) = pk;
          }
      }
    } else {
      // Q panel (head ph): direct scattered bf16 stores (r10-proven)
      int ph = p - 16;
      #pragma unroll
      for (int rt = 0; rt < 2; rt++)
        #pragma unroll
        for (int j = 0; j < 2; j++)
          #pragma unroll
          for (int r = 0; r < 4; r++)
            Q[(m0 + wave * 32 + rt * 16 + lg * 4 + r) * 256 + ph * 32 + j * 16 + li]
              = f2bf(acc[rt][j][r]);
    }
    __syncthreads();   // drains stage(p+1); Bs[buf] reads + WVs writes done
    if (p < 16 && (p & 1)){
      // ctx[h][d][e] += w^T[d][t] * v^T[e][t] over this block's 128 tokens
      int h = p >> 1;
      int dh = wave >> 1, eh = wave & 1;
      f32x4 c = zf;
      #pragma unroll
      for (int ks = 0; ks < 4; ks++){
        short8 aw = *reinterpret_cast<const short8*>(&WVs[0][dh * 16 + li][ks * 32 + lg * 8]);
        short8 bv = *reinterpret_cast<const short8*>(&WVs[1][eh * 16 + li][ks * 32 + lg * 8]);
        c = __builtin_amdgcn_mfma_f32_16x16x32_bf16(aw, bv, c, 0, 0, 0);
      }
      float* cp = ctxp + ((size_t)blk * 8 + h) * 1024;
      #pragma unroll
      for (int r = 0; r < 4; r++)
        cp[(dh * 16 + lg * 4 + r) * 32 + eh * 16 + li] = c[r];
      lds_barrier();   // protect WVs from next K-epi; no global drain
    }
    buf ^= 1;
  }
  sumwp[(size_t)blk * 256 + tid] = sumLds[tid];
}

// ---- K2a: reduce ctx partials 128 -> 16 chunks (full-chip parallel) ----
__global__ __launch_bounds__(256) void k_red1(const float* __restrict__ ctxp,
                                              const float* __restrict__ sumwp,
                                              float* __restrict__ ctxr,
                                              float* __restrict__ sumr){
  int bid = blockIdx.x;              // ((b*8+h)*16+s)
  int s = bid & 15, bh = bid >> 4;
  int b = bh >> 3, h = bh & 7;
  int t = threadIdx.x;
  float a[4] = {0.f, 0.f, 0.f, 0.f};
  #pragma unroll
  for (int k = 0; k < 8; k++){
    const float* cp = ctxp + ((size_t)(b * 128 + s * 8 + k) * 8 + h) * 1024;
    #pragma unroll
    for (int q = 0; q < 4; q++) a[q] += cp[q * 256 + t];
  }
  float* orow = ctxr + (size_t)bid * 1024;
  #pragma unroll
  for (int q = 0; q < 4; q++) orow[q * 256 + t] = a[q];
  if (t < 32){
    float sw = 0.f;
    #pragma unroll
    for (int k = 0; k < 8; k++)
      sw += sumwp[(size_t)(b * 128 + s * 8 + k) * 256 + h * 32 + t];
    sumr[(size_t)bid * 32 + t] = sw;
  }
}

// ---- K2b: final reduce, /sumw, fold Wout -> MT[b][j][hd] bf16 ----
__global__ __launch_bounds__(256) void k_build_m(const float* __restrict__ ctxr,
                                                 const float* __restrict__ sumr,
                                                 const float* __restrict__ Wout,
                                                 unsigned short* __restrict__ MT){
  __shared__ float ctxs[32][33];
  __shared__ float swb[32];
  int b = blockIdx.x >> 3, h = blockIdx.x & 7;
  int bh16 = (b * 8 + h) * 16;
  int t = threadIdx.x;
  int e = t & 31, dq = t >> 5;
  float a0 = 0.f, a1 = 0.f, a2 = 0.f, a3 = 0.f;
  #pragma unroll
  for (int s = 0; s < 16; s++){
    const float* cp = ctxr + (size_t)(bh16 + s) * 1024;
    a0 += cp[dq * 32 + e];         a1 += cp[(dq + 8) * 32 + e];
    a2 += cp[(dq + 16) * 32 + e];  a3 += cp[(dq + 24) * 32 + e];
  }
  if (t < 32){
    float sw = 0.f;
    #pragma unroll
    for (int s = 0; s < 16; s++) sw += sumr[(size_t)(bh16 + s) * 32 + t];
    swb[t] = sw;
  }
  __syncthreads();
  ctxs[dq][e]      = a0 / swb[dq];
  ctxs[dq + 8][e]  = a1 / swb[dq + 8];
  ctxs[dq + 16][e] = a2 / swb[dq + 16];
  ctxs[dq + 24][e] = a3 / swb[dq + 24];
  __syncthreads();
  float s[32];
  #pragma unroll
  for (int d = 0; d < 32; d++) s[d] = 0.f;
  for (int ee = 0; ee < 32; ee++){
    float wv = Wout[(size_t)(h * 32 + ee) * 256 + t];
    #pragma unroll
    for (int d = 0; d < 32; d++) s[d] += ctxs[d][ee] * wv;
  }
  unsigned short* mp = MT + (size_t)b * 65536 + (size_t)t * 256 + h * 32;
  #pragma unroll
  for (int d8 = 0; d8 < 4; d8++){
    short8 pk;
    #pragma unroll
    for (int q = 0; q < 8; q++) pk[q] = (short)f2bf(s[d8 * 8 + q]);
    *reinterpret_cast<short8*>(mp + d8 * 8) = pk;
  }
}

// ---- K3: out = LN( softmax_q(q) @ MT^T ) * gamma ; softmax fused here.
// NO min-waves clamp: register set needs ~130 VGPR (afrag 32 + acc 64 +
// gam 16 + temps); the old (256,4) bound capped at 128 -> potential spill.
// Memory-bound kernel: 3 blocks/CU (12 waves) is ample occupancy. ----
__global__ __launch_bounds__(256) void k_out(const unsigned short* __restrict__ Qm,
                                             const unsigned short* __restrict__ MT,
                                             const float* __restrict__ gamma,
                                             float* __restrict__ out){
  __shared__ unsigned short Bs[64 * 256];  // 32 KB swizzled
  const int blk = blockIdx.x;
  const int b = blk >> 8;
  const size_t m0 = (size_t)blk * 64;
  const int tid = threadIdx.x, wave = tid >> 6, lane = tid & 63;
  const int lg = lane >> 4, li = lane & 15;

  short8 afrag[8];
  {
    const unsigned short* qr = Qm + (m0 + wave * 16 + li) * 256 + lg * 8;
    #pragma unroll
    for (int ks = 0; ks < 8; ks++)
      afrag[ks] = *reinterpret_cast<const short8*>(qr + ks * 32);
  }
  // deferred q-softmax: head ks = cols ks*32..+31; lane holds 8 (lg*8..+7)
  #pragma unroll
  for (int ks = 0; ks < 8; ks++){
    float v[8];
    #pragma unroll
    for (int q = 0; q < 8; q++) v[q] = bf2f((unsigned short)afrag[ks][q]);
    float mx = v[0];
    #pragma unroll
    for (int q = 1; q < 8; q++) mx = fmaxf(mx, v[q]);
    mx = fmaxf(mx, __shfl_xor(mx, 16));
    mx = fmaxf(mx, __shfl_xor(mx, 32));
    float s = 0.f;
    #pragma unroll
    for (int q = 0; q < 8; q++){ v[q] = __expf(v[q] - mx); s += v[q]; }
    s += __shfl_xor(s, 16);
    s += __shfl_xor(s, 32);
    float iv = SCALE / s;
    #pragma unroll
    for (int q = 0; q < 8; q++) afrag[ks][q] = (short)f2bf(v[q] * iv);
  }

  const char* mtb = (const char*)MT + (size_t)b * 131072;
  f32x4 acc[4][4];
  const f32x4 zf = {0.f, 0.f, 0.f, 0.f};
  #pragma unroll
  for (int jb = 0; jb < 4; jb++)
    #pragma unroll
    for (int j = 0; j < 4; j++) acc[jb][j] = zf;

  #pragma unroll
  for (int jb = 0; jb < 4; jb++){
    if (jb) __syncthreads();
    #pragma unroll
    for (int rr = 0; rr < 8; rr++){
      int L = rr * 4096 + tid * 16;
      int G = L ^ (((L >> 9) & 7) << 4);   // pre-swizzled source (rule 21)
      gload_lds16(mtb + (size_t)jb * 32768 + G, (char*)Bs + L);
    }
    __syncthreads();
    #pragma unroll
    for (int ks = 0; ks < 8; ks++)
      #pragma unroll
      for (int j = 0; j < 4; j++){
        int n = j * 16 + li;
        int L = n * 512 + (ks * 32 + lg * 8) * 2;
        short8 bb = *reinterpret_cast<const short8*>((const char*)Bs + (L ^ ((n & 7) << 4)));
        acc[jb][j] = __builtin_amdgcn_mfma_f32_16x16x32_bf16(afrag[ks], bb, acc[jb][j], 0, 0, 0);
      }
  }

  float gam[16];
  #pragma unroll
  for (int jb = 0; jb < 4; jb++)
    #pragma unroll
    for (int j = 0; j < 4; j++) gam[jb * 4 + j] = gamma[jb * 64 + j * 16 + li];
  #pragma unroll
  for (int r = 0; r < 4; r++){
    float s = 0.f, qq = 0.f;
    #pragma unroll
    for (int jb = 0; jb < 4; jb++)
      #pragma unroll
      for (int j = 0; j < 4; j++){ float v = acc[jb][j][r]; s += v; qq += v * v; }
    #pragma unroll
    for (int mm = 1; mm < 16; mm <<= 1){ s += __shfl_xor(s, mm); qq += __shfl_xor(qq, mm); }
    float mu = s * (1.f / 256.f);
    float var = qq * (1.f / 256.f) - mu * mu;
    float inv = rsqrtf(var + EPS);
    float* op = out + (m0 + wave * 16 + lg * 4 + r) * 256;
    #pragma unroll
    for (int jb = 0; jb < 4; jb++)
      #pragma unroll
      for (int j = 0; j < 4; j++)
        op[jb * 64 + j * 16 + li] = (acc[jb][j][r] - mu) * inv * gam[jb * 4 + j];
  }
}

extern "C" void kernel_launch(void* const* d_in, const int* in_sizes, int n_in,
                              void* d_out, int out_size, void* d_ws, size_t ws_size,
                              hipStream_t stream){
  const float* x     = (const float*)d_in[0];
  const float* Wqkv  = (const float*)d_in[1];
  const float* Wout  = (const float*)d_in[2];
  const float* gamma = (const float*)d_in[3];
  float* out = (float*)d_out;

  char* ws = (char*)d_ws;
  size_t off = 0;
  unsigned short* Q   = (unsigned short*)(ws + off); off += (size_t)BATCH * SEQ * 256 * 2;   // 67 MB
  unsigned short* WT  = (unsigned short*)(ws + off); off += (size_t)NQKV * DIN * 2;
  float* ctxp         = (float*)(ws + off);          off += (size_t)1024 * 8 * 1024 * 4;     // 33.6 MB
  float* sumwp        = (float*)(ws + off);          off += (size_t)1024 * 256 * 4;
  float* ctxr         = (float*)(ws + off);          off += (size_t)1024 * 1024 * 4;
  float* sumr         = (float*)(ws + off);          off += (size_t)1024 * 32 * 4;
  unsigned short* MT  = (unsigned short*)(ws + off); off += (size_t)BATCH * 65536 * 2;

  k_wt<<<(NQKV * DIN) / 256, 256, 0, stream>>>(Wqkv, WT);
  k_qkv<<<1024, 256, 0, stream>>>(x, WT, Q, ctxp, sumwp);
  k_red1<<<1024, 256, 0, stream>>>(ctxp, sumwp, ctxr, sumr);
  k_build_m<<<64, 256, 0, stream>>>(ctxr, sumr, Wout, MT);
  k_out<<<2048, 256, 0, stream>>>(Q, MT, gamma, out);
}